// Round 16
// baseline (105.634 us; speedup 1.0000x reference)
//
#include <hip/hip_runtime.h>
#include <math.h>
#include <stdint.h>

#define NPTS 8192
#define TOPK 30
#define BUFSZ 768
#define SENT 0xFFFFFFFFFFFFFFFFULL

// Exact numpy-order key: (float_bits(D) << 32) | j, numpy association order,
// no fma contraction. Unsigned compare == stable top_k order. (Verified r2-r15.)
__device__ __forceinline__ unsigned long long exact_key(const float* __restrict__ X,
                                                        float xi, float yi, float zi, int j) {
#pragma clang fp contract(off)
    float dx = X[j * 3 + 0] - xi;
    float dy = X[j * 3 + 1] - yi;
    float dz = X[j * 3 + 2] - zi;
    float d2 = dx * dx;
    d2 = d2 + dy * dy;
    d2 = d2 + dz * dz;
    float d = sqrtf(d2 + 1e-6f);
    return ((unsigned long long)__float_as_uint(d) << 32) | (unsigned int)j;
}

__device__ __forceinline__ unsigned long long bcast64(unsigned long long v, int src) {
    return (unsigned long long)__shfl((long long)v, src);
}

// Block-cooperative (r15-verified): 4 waves split the 8192 points; each wave
// scans its 2048-pt range for ALL 4 rows. Phase 0 now reuses the wave's own
// first scan tile via float4 (was: 48 scalar loads -> 576 L1 line-touches).
__global__ __launch_bounds__(256)
void knn_topk_kernel(const float* __restrict__ X,
                     const float* __restrict__ mask,
                     float* __restrict__ out)
{
    __shared__ int   buf[4][BUFSZ];   // per-ROW candidate buffers (12.3 KB)
    __shared__ float Tsh[4];          // per-row threshold
    __shared__ int   wcnt[4][4];      // [wave][row] partial counts
    __shared__ int   okf[4];          // per-row status (0 ok, 2 double, 3 halve)

    const int lane  = threadIdx.x & 63;
    const int wv    = threadIdx.x >> 6;
    const int row0  = (int)(blockIdx.x << 2);
    const int myrow = row0 + wv;

    const float mx  = X[myrow * 3 + 0];
    const float myy = X[myrow * 3 + 1];
    const float mz  = X[myrow * 3 + 2];
    // all 4 rows' coords (blockIdx-uniform -> scalar loads)
    const float rx0 = X[(row0+0)*3+0], ry0 = X[(row0+0)*3+1], rz0 = X[(row0+0)*3+2];
    const float rx1 = X[(row0+1)*3+0], ry1 = X[(row0+1)*3+1], rz1 = X[(row0+1)*3+2];
    const float rx2 = X[(row0+2)*3+0], ry2 = X[(row0+2)*3+1], rz2 = X[(row0+2)*3+2];
    const float rx3 = X[(row0+3)*3+0], ry3 = X[(row0+3)*3+1], rz3 = X[(row0+3)*3+2];

    const float4* X4 = (const float4*)X;
    const int base_t = wv << 3;       // my 8 tiles of 256 points

    // ---- phase 0 (fused): threshold for MY row from MY first scan tile
    // (256 pts, 3 float4 loads). T = 4th smallest of 64 per-lane minima
    // (conservative >= sample 4th order stat; E[C] ~ 160). ----
    {
        const int bi = (base_t * 64 + lane) * 3;
        const float4 a0 = X4[bi + 0];
        const float4 a1 = X4[bi + 1];
        const float4 a2 = X4[bi + 2];
        const float dxa = a0.x-mx, dya = a0.y-myy, dza = a0.z-mz;
        const float dxb = a0.w-mx, dyb = a1.x-myy, dzb = a1.y-mz;
        const float dxc = a1.z-mx, dyc = a1.w-myy, dzc = a2.x-mz;
        const float dxd = a2.y-mx, dyd = a2.z-myy, dzd = a2.w-mz;
        const float qa = fmaf(dza,dza,fmaf(dya,dya,dxa*dxa));
        const float qb = fmaf(dzb,dzb,fmaf(dyb,dyb,dxb*dxb));
        const float qc = fmaf(dzc,dzc,fmaf(dyc,dyc,dxc*dxc));
        const float qd = fmaf(dzd,dzd,fmaf(dyd,dyd,dxd*dxd));
        float smin = fminf(fminf(qa, qb), fminf(qc, qd));
#pragma unroll
        for (int k = 2; k <= 64; k <<= 1) {
#pragma unroll
            for (int m = k >> 1; m >= 1; m >>= 1) {
                const float p = __shfl_xor(smin, m);
                const bool tm = (((lane & k) == 0) == ((lane & m) == 0));
                smin = ((smin < p) == tm) ? smin : p;
            }
        }
        const float T4 = __shfl(smin, 3);   // 4th smallest
        if (lane == 0) Tsh[wv] = T4;
    }
    __syncthreads();

    unsigned long long list = SENT;
    bool mydone = false;

// distance+mask for one row against the 4 loaded points
#define ROWM(RX, RY, RZ, TT, MM)                                               \
    {                                                                          \
        const float dxa = a0.x-RX, dya = a0.y-RY, dza = a0.z-RZ;               \
        const float dxb = a0.w-RX, dyb = a1.x-RY, dzb = a1.y-RZ;               \
        const float dxc = a1.z-RX, dyc = a1.w-RY, dzc = a2.x-RZ;               \
        const float dxd = a2.y-RX, dyd = a2.z-RY, dzd = a2.w-RZ;               \
        const float qa = fmaf(dza,dza,fmaf(dya,dya,dxa*dxa));                  \
        const float qb = fmaf(dzb,dzb,fmaf(dyb,dyb,dxb*dxb));                  \
        const float qc = fmaf(dzc,dzc,fmaf(dyc,dyc,dxc*dxc));                  \
        const float qd = fmaf(dzd,dzd,fmaf(dyd,dyd,dxd*dxd));                  \
        unsigned nib = (qa < TT) ? 1u : 0u;                                    \
        nib |= (qb < TT) ? 2u : 0u;                                            \
        nib |= (qc < TT) ? 4u : 0u;                                            \
        nib |= (qd < TT) ? 8u : 0u;                                            \
        MM |= nib << sh;                                                       \
    }

    // ---- certified block loop (typically 1 iteration) ----
    for (;;) {
        const float T0 = Tsh[0], T1 = Tsh[1], T2 = Tsh[2], T3 = Tsh[3];
        unsigned m0 = 0, m1 = 0, m2 = 0, m3 = 0;
#pragma unroll 2
        for (int t8 = 0; t8 < 8; ++t8) {
            const int bi = ((base_t + t8) * 64 + lane) * 3;
            const float4 a0 = X4[bi + 0];
            const float4 a1 = X4[bi + 1];
            const float4 a2 = X4[bi + 2];
            const int sh = t8 * 4;
            ROWM(rx0, ry0, rz0, T0, m0)
            ROWM(rx1, ry1, rz1, T1, m1)
            ROWM(rx2, ry2, rz2, T2, m2)
            ROWM(rx3, ry3, rz3, T3, m3)
        }

        const int c0 = __popc(m0), c1 = __popc(m1), c2 = __popc(m2), c3 = __popc(m3);
        int w0 = c0, w1 = c1, w2 = c2, w3 = c3;
#pragma unroll
        for (int d = 32; d; d >>= 1) {
            w0 += __shfl_xor(w0, d); w1 += __shfl_xor(w1, d);
            w2 += __shfl_xor(w2, d); w3 += __shfl_xor(w3, d);
        }
        if (lane == 0) { wcnt[wv][0] = w0; wcnt[wv][1] = w1;
                         wcnt[wv][2] = w2; wcnt[wv][3] = w3; }
        __syncthreads();

        int C0 = 0, C1 = 0, C2 = 0, C3 = 0, b0 = 0, b1 = 0, b2 = 0, b3 = 0;
#pragma unroll
        for (int w = 0; w < 4; ++w) {
            const int v0 = wcnt[w][0], v1 = wcnt[w][1];
            const int v2 = wcnt[w][2], v3 = wcnt[w][3];
            C0 += v0; C1 += v1; C2 += v2; C3 += v3;
            if (w < wv) { b0 += v0; b1 += v1; b2 += v2; b3 += v3; }
        }
        int p0 = c0, p1 = c1, p2 = c2, p3 = c3;     // inclusive lane prefix
#pragma unroll
        for (int d = 1; d < 64; d <<= 1) {
            const int n0 = __shfl_up(p0, d), n1 = __shfl_up(p1, d);
            const int n2 = __shfl_up(p2, d), n3 = __shfl_up(p3, d);
            if (lane >= d) { p0 += n0; p1 += n1; p2 += n2; p3 += n3; }
        }

#define EXW(MM, CC, BB, PP, CR, R)                                             \
        if (CC >= TOPK + 3 && CC <= BUFSZ) {                                   \
            int off = BB + PP - CR;                                            \
            unsigned mm = MM;                                                  \
            while (mm) {                                                       \
                const int b = __builtin_ctz(mm);                               \
                mm &= mm - 1;                                                  \
                buf[R][off++] =                                                \
                    (base_t + (b >> 2)) * 256 + (lane << 2) + (b & 3);         \
            }                                                                  \
        }
        EXW(m0, C0, b0, p0, c0, 0)
        EXW(m1, C1, b1, p1, c1, 1)
        EXW(m2, C2, b2, p2, c2, 2)
        EXW(m3, C3, b3, p3, c3, 3)
#undef EXW
        __syncthreads();

        // ---- phase 2: wave w resolves row w (verified chunk sort + merge) ----
        const int C = (wv == 0) ? C0 : (wv == 1) ? C1 : (wv == 2) ? C2 : C3;
        int code = 0;
        if (!mydone) {
            if (C < TOPK + 3)      code = 2;
            else if (C > BUFSZ)    code = 3;
            else {
                unsigned long long lst = SENT;
                for (int s0 = 0; s0 < C; s0 += 64) {
                    const int sc = s0 + lane;
                    unsigned long long ck = SENT;
                    if (sc < C) ck = exact_key(X, mx, myy, mz, buf[wv][sc]);
#pragma unroll
                    for (int k = 2; k <= 64; k <<= 1) {
#pragma unroll
                        for (int m = k >> 1; m >= 1; m >>= 1) {
                            const unsigned long long p =
                                (unsigned long long)__shfl_xor((long long)ck, m);
                            const bool tm = (((lane & k) == 0) == ((lane & m) == 0));
                            ck = ((ck < p) == tm) ? ck : p;
                        }
                    }
                    const unsigned long long cg = bcast64(ck, 63 - lane);
                    unsigned long long v = (lane < TOPK) ? lst : cg;
#pragma unroll
                    for (int m = 32; m >= 1; m >>= 1) {
                        const unsigned long long p =
                            (unsigned long long)__shfl_xor((long long)v, m);
                        const bool low = ((lane & m) == 0);
                        v = (low == (v < p)) ? v : p;
                    }
                    lst = (lane < TOPK) ? v : SENT;
                }
                // completeness certificate (verified r10-r15): excluded j has
                // q_fma >= Tu => q_np >= Tu(1-3e-7); cert => D_np(j) > D30.
                const float D30 = __uint_as_float(
                    (uint32_t)(bcast64(lst, TOPK - 1) >> 32));
                const float Tu = Tsh[wv];
                if (fmaf(D30, D30, -1e-6f) < Tu * 0.99995f) {
                    list = lst; mydone = true; code = 0;
                } else code = 2;
            }
        }
        if (lane == 0) okf[wv] = code;
        __syncthreads();
        if ((okf[0] | okf[1] | okf[2] | okf[3]) == 0) break;
        if (lane == 0 && code)
            Tsh[wv] = (code == 2) ? Tsh[wv] * 2.0f : Tsh[wv] * 0.5f;
        __syncthreads();
    }
#undef ROWM

    // ---- emit: wave w writes row w ----
    if (lane < TOPK) {
        const int   li = (int)(uint32_t)(list & 0xFFFFFFFFu);
        const float lv = __uint_as_float((uint32_t)(list >> 32));
        const int base = myrow * TOPK + lane;
        out[base]                   = lv;                     // D_neighbors
        out[NPTS * TOPK + base]     = (float)li;              // E_idx
        out[2 * NPTS * TOPK + base] = mask[myrow] * mask[li]; // mask_neighbors
    }
}

extern "C" void kernel_launch(void* const* d_in, const int* in_sizes, int n_in,
                              void* d_out, int out_size, void* d_ws, size_t ws_size,
                              hipStream_t stream) {
    const float* X    = (const float*)d_in[0];
    const float* mask = (const float*)d_in[1];
    float* out        = (float*)d_out;

    dim3 grid(NPTS / 4), block(256);   // 4 rows/block, cooperative scan
    knn_topk_kernel<<<grid, block, 0, stream>>>(X, mask, out);
}